// Round 3
// baseline (115.450 us; speedup 1.0000x reference)
//
#include <hip/hip_runtime.h>

// Problem constants: B=8, M=N=256, D=512
#define USTR 192   // pair-planes per batch-dir: u = (row>>1) + lane, 0..190

// Raw HW transcendentals: v_exp_f32 is 2^x, v_log_f32 is log2(x).
#define EXP2F(x) __builtin_amdgcn_exp2f(x)
#define LOG2F(x) __builtin_amdgcn_logf(x)

__device__ __forceinline__ void ld4(float d[4], const float* p) {
  float4 v = *(const float4*)p;
  d[0] = v.x; d[1] = v.y; d[2] = v.z; d[3] = v.w;
}

// ---------------------------------------------------------------------------
// Kernel 1: cost GEMM, 32x64 tiles (256 blocks = 1 block/CU), with
//  - row norms fused in-block
//  - double-buffered LDS, BK=32, ONE barrier per K-step
//  - A-pair read as one ds_read_b64
// Output m = exp2(-cost*ig2) written ONCE in forward pair-plane layout:
//   plane u = v+l, lane l, rows 2v,2v+1.  (The mirrored copy for the
//   backward pass is gone: dir=1 blocks read this array with the index
//   transform (u,l,h,c) -> (190-u, 63-l, 1-h, 3-c), which is the same
//   data bit-for-bit.  Halves gemm stores + mAll footprint.)
// ---------------------------------------------------------------------------
__global__ void __launch_bounds__(256) cost_gemm(const float* __restrict__ x,
                                                 const float* __restrict__ y,
                                                 const float* __restrict__ gamma,
                                                 float* __restrict__ mAll) {
  int b = blockIdx.z, mt = blockIdx.y, nt = blockIdx.x;
  int m0 = mt * 32, n0 = nt * 64;
  __shared__ float Xs[2][32][36];
  __shared__ float Ys[2][32][68];
  __shared__ float RxS[32];
  __shared__ float RyS[64];
  int tid = threadIdx.x;
  int row = tid >> 2, cq = tid & 3;       // loader mapping: 64 rows x 4 quads
  int tx = tid & 15, ty = tid >> 4;       // compute mapping: 16 cols x 16 rowpairs
  const float* xb = x + ((size_t)b * 256 + m0) * 512;
  const float* yb = y + ((size_t)b * 256 + n0) * 512;
  float acc[2][4] = {};
  float sx = 0.f, sy = 0.f;               // squared-sum accumulators (norms)
  float4 xv0, xv1, yv0, yv1;

  auto loadTile = [&](int k0) {
    if (tid < 128) {
      xv0 = *(const float4*)(xb + (size_t)row * 512 + k0 + cq * 4);
      xv1 = *(const float4*)(xb + (size_t)row * 512 + k0 + 16 + cq * 4);
    }
    yv0 = *(const float4*)(yb + (size_t)row * 512 + k0 + cq * 4);
    yv1 = *(const float4*)(yb + (size_t)row * 512 + k0 + 16 + cq * 4);
  };
  auto stageTile = [&](int buf) {
    if (tid < 128) {
      sx += xv0.x*xv0.x + xv0.y*xv0.y + xv0.z*xv0.z + xv0.w*xv0.w
          + xv1.x*xv1.x + xv1.y*xv1.y + xv1.z*xv1.z + xv1.w*xv1.w;
      Xs[buf][cq*4+0][row] = xv0.x; Xs[buf][cq*4+1][row] = xv0.y;
      Xs[buf][cq*4+2][row] = xv0.z; Xs[buf][cq*4+3][row] = xv0.w;
      Xs[buf][16+cq*4+0][row] = xv1.x; Xs[buf][16+cq*4+1][row] = xv1.y;
      Xs[buf][16+cq*4+2][row] = xv1.z; Xs[buf][16+cq*4+3][row] = xv1.w;
    }
    sy += yv0.x*yv0.x + yv0.y*yv0.y + yv0.z*yv0.z + yv0.w*yv0.w
        + yv1.x*yv1.x + yv1.y*yv1.y + yv1.z*yv1.z + yv1.w*yv1.w;
    Ys[buf][cq*4+0][row] = yv0.x; Ys[buf][cq*4+1][row] = yv0.y;
    Ys[buf][cq*4+2][row] = yv0.z; Ys[buf][cq*4+3][row] = yv0.w;
    Ys[buf][16+cq*4+0][row] = yv1.x; Ys[buf][16+cq*4+1][row] = yv1.y;
    Ys[buf][16+cq*4+2][row] = yv1.z; Ys[buf][16+cq*4+3][row] = yv1.w;
  };

  loadTile(0);
  stageTile(0);
  for (int t = 0; t < 16; ++t) {
    __syncthreads();                      // buf[t&1] writes visible to all
    if (t < 15) loadTile((t + 1) * 32);   // global->reg, hides under FMAs
    int cb = t & 1;
#pragma unroll
    for (int kk = 0; kk < 32; ++kk) {
      float2 av = *(const float2*)(&Xs[cb][kk][ty * 2]);
      float4 bv = *(const float4*)(&Ys[cb][kk][tx * 4]);
      acc[0][0] += av.x * bv.x; acc[0][1] += av.x * bv.y;
      acc[0][2] += av.x * bv.z; acc[0][3] += av.x * bv.w;
      acc[1][0] += av.y * bv.x; acc[1][1] += av.y * bv.y;
      acc[1][2] += av.y * bv.z; acc[1][3] += av.y * bv.w;
    }
    if (t < 15) stageTile(cb ^ 1);        // other buffer: no hazard w/ readers
  }

  // norms: reduce squared sums over the 4 quad-threads of each row
  sy += __shfl_xor(sy, 1, 64); sy += __shfl_xor(sy, 2, 64);
  if (tid < 128) { sx += __shfl_xor(sx, 1, 64); sx += __shfl_xor(sx, 2, 64); }
  if (cq == 0) {
    RyS[row] = 1.0f / fmaxf(sqrtf(sy), 1e-8f);
    if (tid < 128) RxS[row] = 1.0f / fmaxf(sqrtf(sx), 1e-8f);
  }
  __syncthreads();

  float gv = fmaxf(fabsf(gamma[0]), 1e-4f);
  float ig2 = 1.4426950408889634f / gv;
  float rx[2], ry[4];
#pragma unroll
  for (int r = 0; r < 2; ++r) rx[r] = RxS[ty * 2 + r];
#pragma unroll
  for (int c = 0; c < 4; ++c) ry[c] = RyS[tx * 4 + c];
  int l = nt * 16 + tx;                  // column-group lane
  int v = mt * 16 + ty;                  // row-pair index
  int u = v + l;                         // pair-plane index
  float4 stm[2];
#pragma unroll
  for (int r = 0; r < 2; ++r) {
    float c0 = (1.0f - acc[r][0] * rx[r] * ry[0]) * ig2;
    float c1 = (1.0f - acc[r][1] * rx[r] * ry[1]) * ig2;
    float c2 = (1.0f - acc[r][2] * rx[r] * ry[2]) * ig2;
    float c3 = (1.0f - acc[r][3] * rx[r] * ry[3]) * ig2;
    stm[r] = (float4){EXP2F(-c0), EXP2F(-c1), EXP2F(-c2), EXP2F(-c3)};
  }
  float* mpF = mAll + ((size_t)b * USTR + u) * 512 + l * 8;
  *(float4*)(mpF)     = stm[0];
  *(float4*)(mpF + 4) = stm[1];
}

// ---------------------------------------------------------------------------
// Kernel 2: dual-direction p-pass.  Blocks 0-7: forward p on batch b.
// Blocks 8-15: the SAME recurrence on the REVERSED potentials = backward
// b-pass.  The reversal is done at load time from the single forward mAll:
//   m_rev record (plane u, lane l, half h, elem c)
//     = forward record (plane 190-u, lane 63-l, half 1-h, elem 3-c)
// (one contiguous 2KB segment per wave either way; element permutation is
// free register renaming in loadC).
// One wave per block; lane l owns cols 4l..4l+3; slot t processes rows
// R=2(t-l), R+1 of plane u=t (active iff 0<=t-l<=127).  p = P * 2^Q, Q
// constant per 8-slot epoch (recorded in Qep, renorm at epoch end).
// presh0/presh1 (shfl_up of bot0/bot1) are issued at the END of slot t so
// their latency overlaps stores + prefetch; adj = Q(l-1)-Q(l) is
// epoch-constant, refreshed at renorm.
// E is recovered later as p*b/(m*Z) -- no weights, no log2 on the chain.
// ---------------------------------------------------------------------------
__global__ void __launch_bounds__(64, 1) pass_kernel(const float* __restrict__ mAll,
                                                     float* __restrict__ pAll,
                                                     float* __restrict__ QepAll,
                                                     const float* __restrict__ gamma,
                                                     float* __restrict__ dist_out) {
  int blk = blockIdx.x, l = threadIdx.x;
  int dir = blk >> 3, b = blk & 7;
  float gv = fmaxf(fabsf(gamma[0]), 1e-4f);
  float gl = gv * 0.6931471805599453f;      // R = q * gl
  // dir=0: plane u, lane-offset l*8.  dir=1: plane 190-u, lane-offset (63-l)*8.
  const float* mb = mAll + (size_t)b * USTR * 512 + (dir ? (63 - l) * 8 : l * 8);
  float* pb = pAll + (size_t)blk * USTR * 512 + l * 8;
  float* qe = QepAll + ((size_t)blk * 64 + l) * 24;
  float Pp0 = 0.f, Pp1 = 0.f, Pp2 = 0.f, Pp3 = 0.f;  // row R-1 (own, scaled)
  float bot0 = 0.f, bot1 = 0.f;   // my col-3 values of last pair (for lane l+1)
  int Q = 0;                       // lane scale: p = P * 2^Q
  float ucar = (l == 0) ? 1.0f : 0.f;  // p(R-1, 4l-1); origin seed p(-1,-1)=1
  float presh0 = 0.f, presh1 = 0.f;    // shfl_up(bot0/bot1) pending for next slot
  int adj = 0;                          // Q(l-1) - Q(l), constant within epoch
  float A0[8], A1[8], A2[8], A3[8], A4[8], A5[8], A6[8], A7[8];
  float A8[8], A9[8], A10[8], A11[8], A12[8], A13[8], A14[8], A15[8];
  auto loadC = [&](int t, float* buf) {
    int u = t > 190 ? 190 : t;
    int pu = dir ? 190 - u : u;               // wave-uniform select
    const float* p = mb + (size_t)pu * 512;
    float q0[4], q1[4];
    ld4(q0, p); ld4(q1, p + 4);
    if (dir) {                                // reversed record: free reg renames
      buf[0] = q1[3]; buf[1] = q1[2]; buf[2] = q1[1]; buf[3] = q1[0];
      buf[4] = q0[3]; buf[5] = q0[2]; buf[6] = q0[1]; buf[7] = q0[0];
    } else {
      buf[0] = q0[0]; buf[1] = q0[1]; buf[2] = q0[2]; buf[3] = q0[3];
      buf[4] = q1[0]; buf[5] = q1[1]; buf[6] = q1[2]; buf[7] = q1[3];
    }
  };
  auto body = [&](int t, const float* mm) {
    bool act = (unsigned)(t - l) <= 127u;
    float s0 = (l == 0) ? 0.f : ldexpf(presh0, adj);  // p(R,   4l-1)
    float s1 = (l == 0) ? 0.f : ldexpf(presh1, adj);  // p(R+1, 4l-1)
    // row R
    float v0 = mm[0] * (Pp0 + s0 + ucar);
    float v1 = mm[1] * (Pp1 + v0 + Pp0);
    float v2 = mm[2] * (Pp2 + v1 + Pp1);
    float v3 = mm[3] * (Pp3 + v2 + Pp2);
    // row R+1
    float w0 = mm[4] * (v0 + s1 + s0);
    float w1 = mm[5] * (v1 + w0 + v0);
    float w2 = mm[6] * (v2 + w1 + v1);
    float w3 = mm[7] * (v3 + w2 + v2);
    if (act) {
      float* sp = pb + (size_t)t * 512;
      *(float4*)(sp)     = (float4){v0, v1, v2, v3};
      *(float4*)(sp + 4) = (float4){w0, w1, w2, w3};
      Pp0 = w0; Pp1 = w1; Pp2 = w2; Pp3 = w3;
      ucar = s1; bot0 = v3; bot1 = w3;
      if (dir == 0 && l == 63 && t == 190)
        dist_out[b] = (-(float)Q - LOG2F(w3)) * gl;   // distance, off-loop
    }
    // issue next slot's neighbor shuffles now: latency hides under
    // stores + prefetch loads + loop overhead (off the critical chain)
    presh0 = __shfl_up(bot0, 1);
    presh1 = __shfl_up(bot1, 1);
  };
  auto renorm = [&](int tEnd) {
    if ((unsigned)(tEnd - l) <= 127u) {
      int e = (int)((__float_as_uint(Pp3) >> 23) & 255u) - 127;
      Pp0 = ldexpf(Pp0, -e); Pp1 = ldexpf(Pp1, -e);
      Pp2 = ldexpf(Pp2, -e); Pp3 = ldexpf(Pp3, -e);
      ucar = ldexpf(ucar, -e);
      bot0 = ldexpf(bot0, -e); bot1 = ldexpf(bot1, -e);
      Q += e;
    }
    // bot/Q changed non-uniformly: refresh pipelined shuffles + epoch adj
    presh0 = __shfl_up(bot0, 1);
    presh1 = __shfl_up(bot1, 1);
    adj = __shfl_up(Q, 1) - Q;
  };
  loadC(0, A0);  loadC(1, A1);  loadC(2, A2);  loadC(3, A3);
  loadC(4, A4);  loadC(5, A5);  loadC(6, A6);  loadC(7, A7);
  loadC(8, A8);  loadC(9, A9);  loadC(10, A10); loadC(11, A11);
  loadC(12, A12); loadC(13, A13); loadC(14, A14); loadC(15, A15);
  for (int it = 0; it < 12; ++it) {   // 12 x 16 = 192 slots; last live 190
    int s = it * 16;
    qe[2 * it] = (float)Q;
    body(s + 0, A0); loadC(s + 16, A0);
    body(s + 1, A1); loadC(s + 17, A1);
    body(s + 2, A2); loadC(s + 18, A2);
    body(s + 3, A3); loadC(s + 19, A3);
    body(s + 4, A4); loadC(s + 20, A4);
    body(s + 5, A5); loadC(s + 21, A5);
    body(s + 6, A6); loadC(s + 22, A6);
    body(s + 7, A7); loadC(s + 23, A7);
    renorm(s + 7);
    qe[2 * it + 1] = (float)Q;
    body(s + 8,  A8);  loadC(s + 24, A8);
    body(s + 9,  A9);  loadC(s + 25, A9);
    body(s + 10, A10); loadC(s + 26, A10);
    body(s + 11, A11); loadC(s + 27, A11);
    body(s + 12, A12); loadC(s + 28, A12);
    body(s + 13, A13); loadC(s + 29, A13);
    body(s + 14, A14); loadC(s + 30, A14);
    body(s + 15, A15); loadC(s + 31, A15);
    renorm(s + 15);
  }
}

// ---------------------------------------------------------------------------
// Kernel 3: posterior combine.  E[r][c] = p(r,c) * b(r,c) / (m(r,c) * Z),
// Z = p(255,255).  Scales: p = P*2^Qf, b = B*2^Qb, Z = Zp*2^Zq ->
// E = (P*B)/(M*Zp) * 2^(Qf+Qb-Zq) via ldexp (underflow -> true-zero E).
// b(r,c) sits in the REVERSED pass output at plane 190-v-l, lane 63-l,
// half (1-r&1), element 3-k.  Writes row-major float4 directly to d_out.
// ---------------------------------------------------------------------------
__global__ void __launch_bounds__(256) e_kernel(const float* __restrict__ mAll,
                                                const float* __restrict__ pAll,
                                                const float* __restrict__ QepAll,
                                                float* __restrict__ out) {
  int tid = blockIdx.x * 256 + threadIdx.x;   // = ((b*256 + r)*64 + l)
  int l = tid & 63;
  int r = (tid >> 6) & 255;
  int b = tid >> 14;
  int v = r >> 1, rf = r & 1;
  int uF = v + l;
  int uR = 190 - v - l;
  const float* pF  = pAll + ((size_t)b * USTR + uF) * 512 + l * 8 + rf * 4;
  const float* pRv = pAll + ((size_t)(8 + b) * USTR + uR) * 512 + (63 - l) * 8 + (1 - rf) * 4;
  const float* mF  = mAll + ((size_t)b * USTR + uF) * 512 + l * 8 + rf * 4;
  float P[4], Bv[4], M[4];
  ld4(P, pF); ld4(Bv, pRv); ld4(M, mF);
  float Qf = QepAll[((size_t)b * 64 + l) * 24 + (uF >> 3)];
  float Qb = QepAll[((size_t)(8 + b) * 64 + (63 - l)) * 24 + (uR >> 3)];
  float Zp = pAll[((size_t)b * USTR + 190) * 512 + 511];
  float Zq = QepAll[((size_t)b * 64 + 63) * 24 + 23];
  int e = (int)(Qf + Qb - Zq);
  float inv = 1.0f / Zp;
  float4 o;
  o.x = ldexpf(P[0] * Bv[3] / M[0] * inv, e);
  o.y = ldexpf(P[1] * Bv[2] / M[1] * inv, e);
  o.z = ldexpf(P[2] * Bv[1] / M[2] * inv, e);
  o.w = ldexpf(P[3] * Bv[0] / M[3] * inv, e);
  *(float4*)(out + (size_t)b * 65536 + (size_t)r * 256 + 4 * l) = o;
}

// ---------------------------------------------------------------------------
// Workspace (floats), ~9.5 MB:
//   [4096 floats: reserved]
//   mAll  (8*192*512: potentials, forward pair-planes only)
//   pAll  (16*192*512: p-pass outputs; slots 0-7 fwd, 8-15 reversed)
//   QepAll (16*64*24: per-block per-lane per-epoch scales)
// Alignment (E) and distance go straight into d_out.
// d_out: alignment [0 .. 524287], distance [524288 .. 524295].
// ---------------------------------------------------------------------------
extern "C" void kernel_launch(void* const* d_in, const int* in_sizes, int n_in,
                              void* d_out, int out_size, void* d_ws, size_t ws_size,
                              hipStream_t stream) {
  const float* x = (const float*)d_in[0];
  const float* y = (const float*)d_in[1];
  const float* gamma = (const float*)d_in[2];
  float* out = (float*)d_out;
  float* ws = (float*)d_ws;

  const size_t PMAT_M = (size_t)8 * USTR * 512;   // forward-only potentials
  const size_t PMAT_P = (size_t)16 * USTR * 512;  // both-direction p outputs
  float* mAll   = ws + 4096;
  float* pAll   = mAll + PMAT_M;
  float* QepAll = pAll + PMAT_P;

  cost_gemm<<<dim3(4, 8, 8), 256, 0, stream>>>(x, y, gamma, mAll);
  pass_kernel<<<16, 64, 0, stream>>>(mAll, pAll, QepAll, gamma, out + 524288);
  e_kernel<<<512, 256, 0, stream>>>(mAll, pAll, QepAll, out);
}

// Round 4
// 113.290 us; speedup vs baseline: 1.0191x; 1.0191x over previous
//
#include <hip/hip_runtime.h>

// Problem constants: B=8, M=N=256, D=512
#define USTR 192   // pair-planes per batch-dir: u = (row>>1) + lane, 0..190

// Raw HW transcendentals: v_exp_f32 is 2^x, v_log_f32 is log2(x).
#define EXP2F(x) __builtin_amdgcn_exp2f(x)
#define LOG2F(x) __builtin_amdgcn_logf(x)

__device__ __forceinline__ void ld4(float d[4], const float* p) {
  float4 v = *(const float4*)p;
  d[0] = v.x; d[1] = v.y; d[2] = v.z; d[3] = v.w;
}

// DPP wave_shr:1 — lane l receives x from lane l-1; lane 0 gets 0
// (bound_ctrl).  Pure-VALU (~5 cy) replacement for __shfl_up(x,1)'s
// ds_bpermute (~60-120 cy LDS-class latency, exposed at 1 wave/SIMD).
__device__ __forceinline__ float dpp_shr1_f(float x) {
  int r = __builtin_amdgcn_update_dpp(0, __float_as_int(x),
                                      0x138 /*wave_shr:1*/, 0xF, 0xF, true);
  return __int_as_float(r);
}
__device__ __forceinline__ int dpp_shr1_i(int x) {
  return __builtin_amdgcn_update_dpp(0, x, 0x138, 0xF, 0xF, true);
}

// ---------------------------------------------------------------------------
// Kernel 1: cost GEMM, 32x64 tiles (256 blocks = 1 block/CU), with
//  - row norms fused in-block
//  - double-buffered LDS, BK=32, ONE barrier per K-step
//  - A-pair read as one ds_read_b64
// Output m = exp2(-cost*ig2) written ONCE in forward pair-plane layout:
//   plane u = v+l, lane l, rows 2v,2v+1.  Backward pass reads this array
//   with the index transform (u,l,h,c) -> (190-u, 63-l, 1-h, 3-c).
// ---------------------------------------------------------------------------
__global__ void __launch_bounds__(256) cost_gemm(const float* __restrict__ x,
                                                 const float* __restrict__ y,
                                                 const float* __restrict__ gamma,
                                                 float* __restrict__ mAll) {
  int b = blockIdx.z, mt = blockIdx.y, nt = blockIdx.x;
  int m0 = mt * 32, n0 = nt * 64;
  __shared__ float Xs[2][32][36];
  __shared__ float Ys[2][32][68];
  __shared__ float RxS[32];
  __shared__ float RyS[64];
  int tid = threadIdx.x;
  int row = tid >> 2, cq = tid & 3;       // loader mapping: 64 rows x 4 quads
  int tx = tid & 15, ty = tid >> 4;       // compute mapping: 16 cols x 16 rowpairs
  const float* xb = x + ((size_t)b * 256 + m0) * 512;
  const float* yb = y + ((size_t)b * 256 + n0) * 512;
  float acc[2][4] = {};
  float sx = 0.f, sy = 0.f;               // squared-sum accumulators (norms)
  float4 xv0, xv1, yv0, yv1;

  auto loadTile = [&](int k0) {
    if (tid < 128) {
      xv0 = *(const float4*)(xb + (size_t)row * 512 + k0 + cq * 4);
      xv1 = *(const float4*)(xb + (size_t)row * 512 + k0 + 16 + cq * 4);
    }
    yv0 = *(const float4*)(yb + (size_t)row * 512 + k0 + cq * 4);
    yv1 = *(const float4*)(yb + (size_t)row * 512 + k0 + 16 + cq * 4);
  };
  auto stageTile = [&](int buf) {
    if (tid < 128) {
      sx += xv0.x*xv0.x + xv0.y*xv0.y + xv0.z*xv0.z + xv0.w*xv0.w
          + xv1.x*xv1.x + xv1.y*xv1.y + xv1.z*xv1.z + xv1.w*xv1.w;
      Xs[buf][cq*4+0][row] = xv0.x; Xs[buf][cq*4+1][row] = xv0.y;
      Xs[buf][cq*4+2][row] = xv0.z; Xs[buf][cq*4+3][row] = xv0.w;
      Xs[buf][16+cq*4+0][row] = xv1.x; Xs[buf][16+cq*4+1][row] = xv1.y;
      Xs[buf][16+cq*4+2][row] = xv1.z; Xs[buf][16+cq*4+3][row] = xv1.w;
    }
    sy += yv0.x*yv0.x + yv0.y*yv0.y + yv0.z*yv0.z + yv0.w*yv0.w
        + yv1.x*yv1.x + yv1.y*yv1.y + yv1.z*yv1.z + yv1.w*yv1.w;
    Ys[buf][cq*4+0][row] = yv0.x; Ys[buf][cq*4+1][row] = yv0.y;
    Ys[buf][cq*4+2][row] = yv0.z; Ys[buf][cq*4+3][row] = yv0.w;
    Ys[buf][16+cq*4+0][row] = yv1.x; Ys[buf][16+cq*4+1][row] = yv1.y;
    Ys[buf][16+cq*4+2][row] = yv1.z; Ys[buf][16+cq*4+3][row] = yv1.w;
  };

  loadTile(0);
  stageTile(0);
  for (int t = 0; t < 16; ++t) {
    __syncthreads();                      // buf[t&1] writes visible to all
    if (t < 15) loadTile((t + 1) * 32);   // global->reg, hides under FMAs
    int cb = t & 1;
#pragma unroll
    for (int kk = 0; kk < 32; ++kk) {
      float2 av = *(const float2*)(&Xs[cb][kk][ty * 2]);
      float4 bv = *(const float4*)(&Ys[cb][kk][tx * 4]);
      acc[0][0] += av.x * bv.x; acc[0][1] += av.x * bv.y;
      acc[0][2] += av.x * bv.z; acc[0][3] += av.x * bv.w;
      acc[1][0] += av.y * bv.x; acc[1][1] += av.y * bv.y;
      acc[1][2] += av.y * bv.z; acc[1][3] += av.y * bv.w;
    }
    if (t < 15) stageTile(cb ^ 1);        // other buffer: no hazard w/ readers
  }

  // norms: reduce squared sums over the 4 quad-threads of each row
  sy += __shfl_xor(sy, 1, 64); sy += __shfl_xor(sy, 2, 64);
  if (tid < 128) { sx += __shfl_xor(sx, 1, 64); sx += __shfl_xor(sx, 2, 64); }
  if (cq == 0) {
    RyS[row] = 1.0f / fmaxf(sqrtf(sy), 1e-8f);
    if (tid < 128) RxS[row] = 1.0f / fmaxf(sqrtf(sx), 1e-8f);
  }
  __syncthreads();

  float gv = fmaxf(fabsf(gamma[0]), 1e-4f);
  float ig2 = 1.4426950408889634f / gv;
  float rx[2], ry[4];
#pragma unroll
  for (int r = 0; r < 2; ++r) rx[r] = RxS[ty * 2 + r];
#pragma unroll
  for (int c = 0; c < 4; ++c) ry[c] = RyS[tx * 4 + c];
  int l = nt * 16 + tx;                  // column-group lane
  int v = mt * 16 + ty;                  // row-pair index
  int u = v + l;                         // pair-plane index
  float4 stm[2];
#pragma unroll
  for (int r = 0; r < 2; ++r) {
    float c0 = (1.0f - acc[r][0] * rx[r] * ry[0]) * ig2;
    float c1 = (1.0f - acc[r][1] * rx[r] * ry[1]) * ig2;
    float c2 = (1.0f - acc[r][2] * rx[r] * ry[2]) * ig2;
    float c3 = (1.0f - acc[r][3] * rx[r] * ry[3]) * ig2;
    stm[r] = (float4){EXP2F(-c0), EXP2F(-c1), EXP2F(-c2), EXP2F(-c3)};
  }
  float* mpF = mAll + ((size_t)b * USTR + u) * 512 + l * 8;
  *(float4*)(mpF)     = stm[0];
  *(float4*)(mpF + 4) = stm[1];
}

// ---------------------------------------------------------------------------
// Kernel 2: dual-direction p-pass.  Blocks 0-7: forward p on batch b.
// Blocks 8-15: the SAME recurrence on the REVERSED potentials = backward
// b-pass (reversal done at load time from the single forward mAll).
// One wave per block; lane l owns cols 4l..4l+3; slot t processes rows
// R=2(t-l), R+1 of plane u=t (active iff 0<=t-l<=127).  p = P * 2^Q, Q
// constant per 8-slot epoch (recorded in Qep, renorm at epoch end).
// Left-neighbor handoff (bot0/bot1 of lane l-1) via DPP wave_shr:1 —
// single VALU instr, ~5 cy, lane0 auto-zeroed — instead of ds_bpermute
// whose ~60-120 cy latency was exposed at 1 wave/SIMD.
// E is recovered later as p*b/(m*Z) -- no weights, no log2 on the chain.
// ---------------------------------------------------------------------------
__global__ void __launch_bounds__(64, 1) pass_kernel(const float* __restrict__ mAll,
                                                     float* __restrict__ pAll,
                                                     float* __restrict__ QepAll,
                                                     const float* __restrict__ gamma,
                                                     float* __restrict__ dist_out) {
  int blk = blockIdx.x, l = threadIdx.x;
  int dir = blk >> 3, b = blk & 7;
  float gv = fmaxf(fabsf(gamma[0]), 1e-4f);
  float gl = gv * 0.6931471805599453f;      // R = q * gl
  // dir=0: plane u, lane-offset l*8.  dir=1: plane 190-u, lane-offset (63-l)*8.
  const float* mb = mAll + (size_t)b * USTR * 512 + (dir ? (63 - l) * 8 : l * 8);
  float* pb = pAll + (size_t)blk * USTR * 512 + l * 8;
  float* qe = QepAll + ((size_t)blk * 64 + l) * 24;
  float Pp0 = 0.f, Pp1 = 0.f, Pp2 = 0.f, Pp3 = 0.f;  // row R-1 (own, scaled)
  float bot0 = 0.f, bot1 = 0.f;   // my col-3 values of last pair (for lane l+1)
  int Q = 0;                       // lane scale: p = P * 2^Q
  float ucar = (l == 0) ? 1.0f : 0.f;  // p(R-1, 4l-1); origin seed p(-1,-1)=1
  float presh0 = 0.f, presh1 = 0.f;    // wave_shr1(bot0/bot1) pending for next slot
  int adj = 0;                          // Q(l-1) - Q(l), constant within epoch
  float A0[8], A1[8], A2[8], A3[8], A4[8], A5[8], A6[8], A7[8];
  float A8[8], A9[8], A10[8], A11[8], A12[8], A13[8], A14[8], A15[8];
  auto loadC = [&](int t, float* buf) {
    int u = t > 190 ? 190 : t;
    int pu = dir ? 190 - u : u;               // wave-uniform select
    const float* p = mb + (size_t)pu * 512;
    float q0[4], q1[4];
    ld4(q0, p); ld4(q1, p + 4);
    if (dir) {                                // reversed record: free reg renames
      buf[0] = q1[3]; buf[1] = q1[2]; buf[2] = q1[1]; buf[3] = q1[0];
      buf[4] = q0[3]; buf[5] = q0[2]; buf[6] = q0[1]; buf[7] = q0[0];
    } else {
      buf[0] = q0[0]; buf[1] = q0[1]; buf[2] = q0[2]; buf[3] = q0[3];
      buf[4] = q1[0]; buf[5] = q1[1]; buf[6] = q1[2]; buf[7] = q1[3];
    }
  };
  auto body = [&](int t, const float* mm) {
    bool act = (unsigned)(t - l) <= 127u;
    // lane 0: presh* are 0 (DPP bound_ctrl) and ldexp(0,e)=0 -> no select
    float s0 = ldexpf(presh0, adj);  // p(R,   4l-1)
    float s1 = ldexpf(presh1, adj);  // p(R+1, 4l-1)
    // row R
    float v0 = mm[0] * (Pp0 + s0 + ucar);
    float v1 = mm[1] * (Pp1 + v0 + Pp0);
    float v2 = mm[2] * (Pp2 + v1 + Pp1);
    float v3 = mm[3] * (Pp3 + v2 + Pp2);
    // row R+1
    float w0 = mm[4] * (v0 + s1 + s0);
    float w1 = mm[5] * (v1 + w0 + v0);
    float w2 = mm[6] * (v2 + w1 + v1);
    float w3 = mm[7] * (v3 + w2 + v2);
    if (act) {
      float* sp = pb + (size_t)t * 512;
      *(float4*)(sp)     = (float4){v0, v1, v2, v3};
      *(float4*)(sp + 4) = (float4){w0, w1, w2, w3};
      Pp0 = w0; Pp1 = w1; Pp2 = w2; Pp3 = w3;
      ucar = s1; bot0 = v3; bot1 = w3;
      if (dir == 0 && l == 63 && t == 190)
        dist_out[b] = (-(float)Q - LOG2F(w3)) * gl;   // distance, off-loop
    }
    // next slot's neighbor handoff: single-VALU DPP, negligible latency
    presh0 = dpp_shr1_f(bot0);
    presh1 = dpp_shr1_f(bot1);
  };
  auto renorm = [&](int tEnd) {
    if ((unsigned)(tEnd - l) <= 127u) {
      int e = (int)((__float_as_uint(Pp3) >> 23) & 255u) - 127;
      Pp0 = ldexpf(Pp0, -e); Pp1 = ldexpf(Pp1, -e);
      Pp2 = ldexpf(Pp2, -e); Pp3 = ldexpf(Pp3, -e);
      ucar = ldexpf(ucar, -e);
      bot0 = ldexpf(bot0, -e); bot1 = ldexpf(bot1, -e);
      Q += e;
    }
    // bot/Q changed non-uniformly: refresh pipelined handoff + epoch adj
    presh0 = dpp_shr1_f(bot0);
    presh1 = dpp_shr1_f(bot1);
    adj = dpp_shr1_i(Q) - Q;   // lane0: 0-Q, harmless (ldexp of 0)
  };
  loadC(0, A0);  loadC(1, A1);  loadC(2, A2);  loadC(3, A3);
  loadC(4, A4);  loadC(5, A5);  loadC(6, A6);  loadC(7, A7);
  loadC(8, A8);  loadC(9, A9);  loadC(10, A10); loadC(11, A11);
  loadC(12, A12); loadC(13, A13); loadC(14, A14); loadC(15, A15);
  for (int it = 0; it < 12; ++it) {   // 12 x 16 = 192 slots; last live 190
    int s = it * 16;
    qe[2 * it] = (float)Q;
    body(s + 0, A0); loadC(s + 16, A0);
    body(s + 1, A1); loadC(s + 17, A1);
    body(s + 2, A2); loadC(s + 18, A2);
    body(s + 3, A3); loadC(s + 19, A3);
    body(s + 4, A4); loadC(s + 20, A4);
    body(s + 5, A5); loadC(s + 21, A5);
    body(s + 6, A6); loadC(s + 22, A6);
    body(s + 7, A7); loadC(s + 23, A7);
    renorm(s + 7);
    qe[2 * it + 1] = (float)Q;
    body(s + 8,  A8);  loadC(s + 24, A8);
    body(s + 9,  A9);  loadC(s + 25, A9);
    body(s + 10, A10); loadC(s + 26, A10);
    body(s + 11, A11); loadC(s + 27, A11);
    body(s + 12, A12); loadC(s + 28, A12);
    body(s + 13, A13); loadC(s + 29, A13);
    body(s + 14, A14); loadC(s + 30, A14);
    body(s + 15, A15); loadC(s + 31, A15);
    renorm(s + 15);
  }
}

// ---------------------------------------------------------------------------
// Kernel 3: posterior combine.  E[r][c] = p(r,c) * b(r,c) / (m(r,c) * Z),
// Z = p(255,255).  Scales: p = P*2^Qf, b = B*2^Qb, Z = Zp*2^Zq ->
// E = (P*B)/(M*Zp) * 2^(Qf+Qb-Zq) via ldexp (underflow -> true-zero E).
// b(r,c) sits in the REVERSED pass output at plane 190-v-l, lane 63-l,
// half (1-r&1), element 3-k.  Writes row-major float4 directly to d_out.
// ---------------------------------------------------------------------------
__global__ void __launch_bounds__(256) e_kernel(const float* __restrict__ mAll,
                                                const float* __restrict__ pAll,
                                                const float* __restrict__ QepAll,
                                                float* __restrict__ out) {
  int tid = blockIdx.x * 256 + threadIdx.x;   // = ((b*256 + r)*64 + l)
  int l = tid & 63;
  int r = (tid >> 6) & 255;
  int b = tid >> 14;
  int v = r >> 1, rf = r & 1;
  int uF = v + l;
  int uR = 190 - v - l;
  const float* pF  = pAll + ((size_t)b * USTR + uF) * 512 + l * 8 + rf * 4;
  const float* pRv = pAll + ((size_t)(8 + b) * USTR + uR) * 512 + (63 - l) * 8 + (1 - rf) * 4;
  const float* mF  = mAll + ((size_t)b * USTR + uF) * 512 + l * 8 + rf * 4;
  float P[4], Bv[4], M[4];
  ld4(P, pF); ld4(Bv, pRv); ld4(M, mF);
  float Qf = QepAll[((size_t)b * 64 + l) * 24 + (uF >> 3)];
  float Qb = QepAll[((size_t)(8 + b) * 64 + (63 - l)) * 24 + (uR >> 3)];
  float Zp = pAll[((size_t)b * USTR + 190) * 512 + 511];
  float Zq = QepAll[((size_t)b * 64 + 63) * 24 + 23];
  int e = (int)(Qf + Qb - Zq);
  float inv = 1.0f / Zp;
  float4 o;
  o.x = ldexpf(P[0] * Bv[3] / M[0] * inv, e);
  o.y = ldexpf(P[1] * Bv[2] / M[1] * inv, e);
  o.z = ldexpf(P[2] * Bv[1] / M[2] * inv, e);
  o.w = ldexpf(P[3] * Bv[0] / M[3] * inv, e);
  *(float4*)(out + (size_t)b * 65536 + (size_t)r * 256 + 4 * l) = o;
}

// ---------------------------------------------------------------------------
// Workspace (floats), ~9.5 MB:
//   [4096 floats: reserved]
//   mAll  (8*192*512: potentials, forward pair-planes only)
//   pAll  (16*192*512: p-pass outputs; slots 0-7 fwd, 8-15 reversed)
//   QepAll (16*64*24: per-block per-lane per-epoch scales)
// Alignment (E) and distance go straight into d_out.
// d_out: alignment [0 .. 524287], distance [524288 .. 524295].
// ---------------------------------------------------------------------------
extern "C" void kernel_launch(void* const* d_in, const int* in_sizes, int n_in,
                              void* d_out, int out_size, void* d_ws, size_t ws_size,
                              hipStream_t stream) {
  const float* x = (const float*)d_in[0];
  const float* y = (const float*)d_in[1];
  const float* gamma = (const float*)d_in[2];
  float* out = (float*)d_out;
  float* ws = (float*)d_ws;

  const size_t PMAT_M = (size_t)8 * USTR * 512;   // forward-only potentials
  const size_t PMAT_P = (size_t)16 * USTR * 512;  // both-direction p outputs
  float* mAll   = ws + 4096;
  float* pAll   = mAll + PMAT_M;
  float* QepAll = pAll + PMAT_P;

  cost_gemm<<<dim3(4, 8, 8), 256, 0, stream>>>(x, y, gamma, mAll);
  pass_kernel<<<16, 64, 0, stream>>>(mAll, pAll, QepAll, gamma, out + 524288);
  e_kernel<<<512, 256, 0, stream>>>(mAll, pAll, QepAll, out);
}

// Round 5
// 107.818 us; speedup vs baseline: 1.0708x; 1.0507x over previous
//
#include <hip/hip_runtime.h>

// Problem constants: B=8, M=N=256, D=512
#define USTR 192   // pair-planes per batch-dir: u = (row>>1) + lane, 0..190

// Raw HW transcendentals: v_exp_f32 is 2^x, v_log_f32 is log2(x).
#define EXP2F(x) __builtin_amdgcn_exp2f(x)
#define LOG2F(x) __builtin_amdgcn_logf(x)

__device__ __forceinline__ void ld4(float d[4], const float* p) {
  float4 v = *(const float4*)p;
  d[0] = v.x; d[1] = v.y; d[2] = v.z; d[3] = v.w;
}

// DPP wave_shr:1 — lane l receives x from lane l-1; lane 0 gets 0
// (bound_ctrl).  Pure-VALU (~5 cy) replacement for __shfl_up(x,1)'s
// ds_bpermute (~60-120 cy LDS-class latency, exposed at 1 wave/SIMD).
__device__ __forceinline__ float dpp_shr1_f(float x) {
  int r = __builtin_amdgcn_update_dpp(0, __float_as_int(x),
                                      0x138 /*wave_shr:1*/, 0xF, 0xF, true);
  return __int_as_float(r);
}
__device__ __forceinline__ int dpp_shr1_i(int x) {
  return __builtin_amdgcn_update_dpp(0, x, 0x138, 0xF, 0xF, true);
}

// ---------------------------------------------------------------------------
// Kernel 1: cost GEMM, 32x64 tiles (256 blocks = 1 block/CU), with
//  - row norms fused in-block
//  - double-buffered LDS, BK=32, ONE barrier per K-step
//  - A-pair read as one ds_read_b64
// Output m = exp2(-cost*ig2) written ONCE in forward pair-plane layout:
//   plane u = v+l, lane l, rows 2v,2v+1.  Backward pass reads this array
//   with the index transform (u,l,h,c) -> (190-u, 63-l, 1-h, 3-c).
// ---------------------------------------------------------------------------
__global__ void __launch_bounds__(256) cost_gemm(const float* __restrict__ x,
                                                 const float* __restrict__ y,
                                                 const float* __restrict__ gamma,
                                                 float* __restrict__ mAll) {
  int b = blockIdx.z, mt = blockIdx.y, nt = blockIdx.x;
  int m0 = mt * 32, n0 = nt * 64;
  __shared__ float Xs[2][32][36];
  __shared__ float Ys[2][32][68];
  __shared__ float RxS[32];
  __shared__ float RyS[64];
  int tid = threadIdx.x;
  int row = tid >> 2, cq = tid & 3;       // loader mapping: 64 rows x 4 quads
  int tx = tid & 15, ty = tid >> 4;       // compute mapping: 16 cols x 16 rowpairs
  const float* xb = x + ((size_t)b * 256 + m0) * 512;
  const float* yb = y + ((size_t)b * 256 + n0) * 512;
  float acc[2][4] = {};
  float sx = 0.f, sy = 0.f;               // squared-sum accumulators (norms)
  float4 xv0, xv1, yv0, yv1;

  auto loadTile = [&](int k0) {
    if (tid < 128) {
      xv0 = *(const float4*)(xb + (size_t)row * 512 + k0 + cq * 4);
      xv1 = *(const float4*)(xb + (size_t)row * 512 + k0 + 16 + cq * 4);
    }
    yv0 = *(const float4*)(yb + (size_t)row * 512 + k0 + cq * 4);
    yv1 = *(const float4*)(yb + (size_t)row * 512 + k0 + 16 + cq * 4);
  };
  auto stageTile = [&](int buf) {
    if (tid < 128) {
      sx += xv0.x*xv0.x + xv0.y*xv0.y + xv0.z*xv0.z + xv0.w*xv0.w
          + xv1.x*xv1.x + xv1.y*xv1.y + xv1.z*xv1.z + xv1.w*xv1.w;
      Xs[buf][cq*4+0][row] = xv0.x; Xs[buf][cq*4+1][row] = xv0.y;
      Xs[buf][cq*4+2][row] = xv0.z; Xs[buf][cq*4+3][row] = xv0.w;
      Xs[buf][16+cq*4+0][row] = xv1.x; Xs[buf][16+cq*4+1][row] = xv1.y;
      Xs[buf][16+cq*4+2][row] = xv1.z; Xs[buf][16+cq*4+3][row] = xv1.w;
    }
    sy += yv0.x*yv0.x + yv0.y*yv0.y + yv0.z*yv0.z + yv0.w*yv0.w
        + yv1.x*yv1.x + yv1.y*yv1.y + yv1.z*yv1.z + yv1.w*yv1.w;
    Ys[buf][cq*4+0][row] = yv0.x; Ys[buf][cq*4+1][row] = yv0.y;
    Ys[buf][cq*4+2][row] = yv0.z; Ys[buf][cq*4+3][row] = yv0.w;
    Ys[buf][16+cq*4+0][row] = yv1.x; Ys[buf][16+cq*4+1][row] = yv1.y;
    Ys[buf][16+cq*4+2][row] = yv1.z; Ys[buf][16+cq*4+3][row] = yv1.w;
  };

  loadTile(0);
  stageTile(0);
  for (int t = 0; t < 16; ++t) {
    __syncthreads();                      // buf[t&1] writes visible to all
    if (t < 15) loadTile((t + 1) * 32);   // global->reg, hides under FMAs
    int cb = t & 1;
#pragma unroll
    for (int kk = 0; kk < 32; ++kk) {
      float2 av = *(const float2*)(&Xs[cb][kk][ty * 2]);
      float4 bv = *(const float4*)(&Ys[cb][kk][tx * 4]);
      acc[0][0] += av.x * bv.x; acc[0][1] += av.x * bv.y;
      acc[0][2] += av.x * bv.z; acc[0][3] += av.x * bv.w;
      acc[1][0] += av.y * bv.x; acc[1][1] += av.y * bv.y;
      acc[1][2] += av.y * bv.z; acc[1][3] += av.y * bv.w;
    }
    if (t < 15) stageTile(cb ^ 1);        // other buffer: no hazard w/ readers
  }

  // norms: reduce squared sums over the 4 quad-threads of each row
  sy += __shfl_xor(sy, 1, 64); sy += __shfl_xor(sy, 2, 64);
  if (tid < 128) { sx += __shfl_xor(sx, 1, 64); sx += __shfl_xor(sx, 2, 64); }
  if (cq == 0) {
    RyS[row] = 1.0f / fmaxf(sqrtf(sy), 1e-8f);
    if (tid < 128) RxS[row] = 1.0f / fmaxf(sqrtf(sx), 1e-8f);
  }
  __syncthreads();

  float gv = fmaxf(fabsf(gamma[0]), 1e-4f);
  float ig2 = 1.4426950408889634f / gv;
  float rx[2], ry[4];
#pragma unroll
  for (int r = 0; r < 2; ++r) rx[r] = RxS[ty * 2 + r];
#pragma unroll
  for (int c = 0; c < 4; ++c) ry[c] = RyS[tx * 4 + c];
  int l = nt * 16 + tx;                  // column-group lane
  int v = mt * 16 + ty;                  // row-pair index
  int u = v + l;                         // pair-plane index
  float4 stm[2];
#pragma unroll
  for (int r = 0; r < 2; ++r) {
    float c0 = (1.0f - acc[r][0] * rx[r] * ry[0]) * ig2;
    float c1 = (1.0f - acc[r][1] * rx[r] * ry[1]) * ig2;
    float c2 = (1.0f - acc[r][2] * rx[r] * ry[2]) * ig2;
    float c3 = (1.0f - acc[r][3] * rx[r] * ry[3]) * ig2;
    stm[r] = (float4){EXP2F(-c0), EXP2F(-c1), EXP2F(-c2), EXP2F(-c3)};
  }
  float* mpF = mAll + ((size_t)b * USTR + u) * 512 + l * 8;
  *(float4*)(mpF)     = stm[0];
  *(float4*)(mpF + 4) = stm[1];
}

// ---------------------------------------------------------------------------
// Kernel 2: dual-direction p-pass, DIR-templated chain.
// Blocks 0-7: forward p on batch b.  Blocks 8-15: same recurrence on the
// load-time-reversed potentials = backward b-pass.  DIR is compile-time ->
// the record reversal in loadC is pure SSA renaming (zero v_mov).
//
// Predication removal: stores + state updates are UNCONDITIONAL.
//  - pre-activation (t<l): all inputs are exactly 0 (DPP bound_ctrl zeroes
//    lane0; neighbor bot is 0 until its own activation) -> state stays 0,
//    bit-identical to the predicated version at activation t=l.
//  - post-deactivation (t>l+127): garbage is finite-positive (products of
//    m<=1 plus sums, growth <=3^63 < FLT_MAX), stored only to (plane,lane)
//    records e_kernel never reads (it reads v=uF-l in [0,127] only), and
//    every value a still-active consumer reads was produced one slot before
//    the producer's first garbage update.
//  - renorm stays predicated: it mutates Q, which e_kernel DOES read.
// This deletes ~8 v_cndmask + v_cmp per slot from an issue-bound loop.
// ---------------------------------------------------------------------------
template<int DIR>
__device__ __forceinline__ void run_chain(const float* __restrict__ mAll,
                                          float* __restrict__ pAll,
                                          float* __restrict__ QepAll,
                                          float gl, int blk, int l,
                                          float* __restrict__ dist_out) {
  int b = blk & 7;
  // DIR=0: plane u, lane-offset l*8.  DIR=1: plane 190-u, lane-offset (63-l)*8.
  const float* mb = mAll + (size_t)b * USTR * 512 + (DIR ? (63 - l) * 8 : l * 8);
  float* pb = pAll + (size_t)blk * USTR * 512 + l * 8;
  float* qe = QepAll + ((size_t)blk * 64 + l) * 24;
  float Pp0 = 0.f, Pp1 = 0.f, Pp2 = 0.f, Pp3 = 0.f;  // row R-1 (own, scaled)
  float bot0 = 0.f, bot1 = 0.f;   // my col-3 values of last pair (for lane l+1)
  int Q = 0;                       // lane scale: p = P * 2^Q
  float ucar = (l == 0) ? 1.0f : 0.f;  // p(R-1, 4l-1); origin seed p(-1,-1)=1
  float presh0 = 0.f, presh1 = 0.f;    // wave_shr1(bot0/bot1) pending for next slot
  int adj = 0;                          // Q(l-1) - Q(l), constant within epoch
  float A0[8], A1[8], A2[8], A3[8], A4[8], A5[8], A6[8], A7[8];
  float A8[8], A9[8], A10[8], A11[8], A12[8], A13[8], A14[8], A15[8];
  auto loadC = [&](int t, float* buf) {
    int u = t > 190 ? 190 : t;
    int pu = DIR ? 190 - u : u;               // compile-time select
    const float* p = mb + (size_t)pu * 512;
    float q0[4], q1[4];
    ld4(q0, p); ld4(q1, p + 4);
    if (DIR) {                                // reversed record: free SSA renames
      buf[0] = q1[3]; buf[1] = q1[2]; buf[2] = q1[1]; buf[3] = q1[0];
      buf[4] = q0[3]; buf[5] = q0[2]; buf[6] = q0[1]; buf[7] = q0[0];
    } else {
      buf[0] = q0[0]; buf[1] = q0[1]; buf[2] = q0[2]; buf[3] = q0[3];
      buf[4] = q1[0]; buf[5] = q1[1]; buf[6] = q1[2]; buf[7] = q1[3];
    }
  };
  auto body = [&](int t, const float* mm) {
    // lane 0: presh* are 0 (DPP bound_ctrl) and ldexp(0,e)=0 -> no select
    float s0 = ldexpf(presh0, adj);  // p(R,   4l-1)
    float s1 = ldexpf(presh1, adj);  // p(R+1, 4l-1)
    // row R
    float v0 = mm[0] * (Pp0 + s0 + ucar);
    float v1 = mm[1] * (Pp1 + v0 + Pp0);
    float v2 = mm[2] * (Pp2 + v1 + Pp1);
    float v3 = mm[3] * (Pp3 + v2 + Pp2);
    // row R+1
    float w0 = mm[4] * (v0 + s1 + s0);
    float w1 = mm[5] * (v1 + w0 + v0);
    float w2 = mm[6] * (v2 + w1 + v1);
    float w3 = mm[7] * (v3 + w2 + v2);
    float* sp = pb + (size_t)t * 512;          // unconditional (safe, see above)
    *(float4*)(sp)     = (float4){v0, v1, v2, v3};
    *(float4*)(sp + 4) = (float4){w0, w1, w2, w3};
    Pp0 = w0; Pp1 = w1; Pp2 = w2; Pp3 = w3;
    ucar = s1; bot0 = v3; bot1 = w3;
    if (DIR == 0 && l == 63 && t == 190)
      dist_out[b] = (-(float)Q - LOG2F(w3)) * gl;   // distance, off-loop
    // next slot's neighbor handoff: single-VALU DPP, negligible latency
    presh0 = dpp_shr1_f(bot0);
    presh1 = dpp_shr1_f(bot1);
  };
  auto renorm = [&](int tEnd) {
    if ((unsigned)(tEnd - l) <= 127u) {   // MUST stay predicated (Q is read)
      int e = (int)((__float_as_uint(Pp3) >> 23) & 255u) - 127;
      Pp0 = ldexpf(Pp0, -e); Pp1 = ldexpf(Pp1, -e);
      Pp2 = ldexpf(Pp2, -e); Pp3 = ldexpf(Pp3, -e);
      ucar = ldexpf(ucar, -e);
      bot0 = ldexpf(bot0, -e); bot1 = ldexpf(bot1, -e);
      Q += e;
    }
    // bot/Q changed non-uniformly: refresh pipelined handoff + epoch adj
    presh0 = dpp_shr1_f(bot0);
    presh1 = dpp_shr1_f(bot1);
    adj = dpp_shr1_i(Q) - Q;   // lane0: 0-Q, harmless (ldexp of 0)
  };
  loadC(0, A0);  loadC(1, A1);  loadC(2, A2);  loadC(3, A3);
  loadC(4, A4);  loadC(5, A5);  loadC(6, A6);  loadC(7, A7);
  loadC(8, A8);  loadC(9, A9);  loadC(10, A10); loadC(11, A11);
  loadC(12, A12); loadC(13, A13); loadC(14, A14); loadC(15, A15);
  for (int it = 0; it < 12; ++it) {   // 12 x 16 = 192 slots; last live 190
    int s = it * 16;
    qe[2 * it] = (float)Q;
    body(s + 0, A0); loadC(s + 16, A0);
    body(s + 1, A1); loadC(s + 17, A1);
    body(s + 2, A2); loadC(s + 18, A2);
    body(s + 3, A3); loadC(s + 19, A3);
    body(s + 4, A4); loadC(s + 20, A4);
    body(s + 5, A5); loadC(s + 21, A5);
    body(s + 6, A6); loadC(s + 22, A6);
    body(s + 7, A7); loadC(s + 23, A7);
    renorm(s + 7);
    qe[2 * it + 1] = (float)Q;
    body(s + 8,  A8);  loadC(s + 24, A8);
    body(s + 9,  A9);  loadC(s + 25, A9);
    body(s + 10, A10); loadC(s + 26, A10);
    body(s + 11, A11); loadC(s + 27, A11);
    body(s + 12, A12); loadC(s + 28, A12);
    body(s + 13, A13); loadC(s + 29, A13);
    body(s + 14, A14); loadC(s + 30, A14);
    body(s + 15, A15); loadC(s + 31, A15);
    renorm(s + 15);
  }
}

__global__ void __launch_bounds__(64, 1) pass_kernel(const float* __restrict__ mAll,
                                                     float* __restrict__ pAll,
                                                     float* __restrict__ QepAll,
                                                     const float* __restrict__ gamma,
                                                     float* __restrict__ dist_out) {
  int blk = blockIdx.x, l = threadIdx.x;
  float gv = fmaxf(fabsf(gamma[0]), 1e-4f);
  float gl = gv * 0.6931471805599453f;      // R = q * gl
  if (blk < 8) run_chain<0>(mAll, pAll, QepAll, gl, blk, l, dist_out);
  else         run_chain<1>(mAll, pAll, QepAll, gl, blk, l, dist_out);
}

// ---------------------------------------------------------------------------
// Kernel 3: posterior combine.  E[r][c] = p(r,c) * b(r,c) / (m(r,c) * Z),
// Z = p(255,255).  Scales: p = P*2^Qf, b = B*2^Qb, Z = Zp*2^Zq ->
// E = (P*B)/(M*Zp) * 2^(Qf+Qb-Zq) via ldexp (underflow -> true-zero E).
// b(r,c) sits in the REVERSED pass output at plane 190-v-l, lane 63-l,
// half (1-r&1), element 3-k.  Writes row-major float4 directly to d_out.
// ---------------------------------------------------------------------------
__global__ void __launch_bounds__(256) e_kernel(const float* __restrict__ mAll,
                                                const float* __restrict__ pAll,
                                                const float* __restrict__ QepAll,
                                                float* __restrict__ out) {
  int tid = blockIdx.x * 256 + threadIdx.x;   // = ((b*256 + r)*64 + l)
  int l = tid & 63;
  int r = (tid >> 6) & 255;
  int b = tid >> 14;
  int v = r >> 1, rf = r & 1;
  int uF = v + l;
  int uR = 190 - v - l;
  const float* pF  = pAll + ((size_t)b * USTR + uF) * 512 + l * 8 + rf * 4;
  const float* pRv = pAll + ((size_t)(8 + b) * USTR + uR) * 512 + (63 - l) * 8 + (1 - rf) * 4;
  const float* mF  = mAll + ((size_t)b * USTR + uF) * 512 + l * 8 + rf * 4;
  float P[4], Bv[4], M[4];
  ld4(P, pF); ld4(Bv, pRv); ld4(M, mF);
  float Qf = QepAll[((size_t)b * 64 + l) * 24 + (uF >> 3)];
  float Qb = QepAll[((size_t)(8 + b) * 64 + (63 - l)) * 24 + (uR >> 3)];
  float Zp = pAll[((size_t)b * USTR + 190) * 512 + 511];
  float Zq = QepAll[((size_t)b * 64 + 63) * 24 + 23];
  int e = (int)(Qf + Qb - Zq);
  float inv = 1.0f / Zp;
  float4 o;
  o.x = ldexpf(P[0] * Bv[3] / M[0] * inv, e);
  o.y = ldexpf(P[1] * Bv[2] / M[1] * inv, e);
  o.z = ldexpf(P[2] * Bv[1] / M[2] * inv, e);
  o.w = ldexpf(P[3] * Bv[0] / M[3] * inv, e);
  *(float4*)(out + (size_t)b * 65536 + (size_t)r * 256 + 4 * l) = o;
}

// ---------------------------------------------------------------------------
// Workspace (floats), ~9.5 MB:
//   [4096 floats: reserved]
//   mAll  (8*192*512: potentials, forward pair-planes only)
//   pAll  (16*192*512: p-pass outputs; slots 0-7 fwd, 8-15 reversed)
//   QepAll (16*64*24: per-block per-lane per-epoch scales)
// Alignment (E) and distance go straight into d_out.
// d_out: alignment [0 .. 524287], distance [524288 .. 524295].
// ---------------------------------------------------------------------------
extern "C" void kernel_launch(void* const* d_in, const int* in_sizes, int n_in,
                              void* d_out, int out_size, void* d_ws, size_t ws_size,
                              hipStream_t stream) {
  const float* x = (const float*)d_in[0];
  const float* y = (const float*)d_in[1];
  const float* gamma = (const float*)d_in[2];
  float* out = (float*)d_out;
  float* ws = (float*)d_ws;

  const size_t PMAT_M = (size_t)8 * USTR * 512;   // forward-only potentials
  const size_t PMAT_P = (size_t)16 * USTR * 512;  // both-direction p outputs
  float* mAll   = ws + 4096;
  float* pAll   = mAll + PMAT_M;
  float* QepAll = pAll + PMAT_P;

  cost_gemm<<<dim3(4, 8, 8), 256, 0, stream>>>(x, y, gamma, mAll);
  pass_kernel<<<16, 64, 0, stream>>>(mAll, pAll, QepAll, gamma, out + 524288);
  e_kernel<<<512, 256, 0, stream>>>(mAll, pAll, QepAll, out);
}